// Round 12
// baseline (157.134 us; speedup 1.0000x reference)
//
#include <hip/hip_runtime.h>

#define NTOK 2048
#define CDIM 1024
#define NHEAD 16
#define HDIM 64
#define NFRM 8
#define FTOK 256

typedef unsigned short ushort;
typedef unsigned long long u64;
typedef __attribute__((ext_vector_type(8))) short short8;     // 8 bf16 = 4 VGPRs (MFMA A/B frag)
typedef __attribute__((ext_vector_type(8))) ushort ushort8;
typedef __attribute__((ext_vector_type(4))) ushort ushort4v;
typedef __attribute__((ext_vector_type(4))) float floatx4;    // MFMA C/D frag

__device__ __forceinline__ ushort f2bf(float f) {
    unsigned int u = __float_as_uint(f);
    return (ushort)((u + 0x7fffu + ((u >> 16) & 1u)) >> 16);   // RNE
}

// async global->LDS, 16B per lane; LDS dest = wave-uniform base + lane*16
__device__ __forceinline__ void gload_lds16(const void* g, void* l) {
    __builtin_amdgcn_global_load_lds(
        (const __attribute__((address_space(1))) unsigned int*)(uintptr_t)g,
        (__attribute__((address_space(3))) unsigned int*)(unsigned int)(uintptr_t)l,
        16, 0, 0);
}

// ---------------------------------------------------------------------------
// Fused prep: [0,2048) x fp32->bf16 ; [2048,2816) Wqkv^T ; [2816,3072) Wproj^T
// [3072] hub bitmask
// ---------------------------------------------------------------------------
__global__ __launch_bounds__(256)
void prep_kernel(const float* __restrict__ x, ushort* __restrict__ xb,
                 const float* __restrict__ Wqkv, ushort* __restrict__ wqkvT,
                 const float* __restrict__ Wproj, ushort* __restrict__ wprojT,
                 const int* __restrict__ is_hub, u64* __restrict__ hubmask)
{
    __shared__ ushort LT[64][72];   // [n][k]
    const int b = blockIdx.x, t = threadIdx.x;

    if (b < 2048) {                 // convx: 2048 blocks x 256 float4
        int i = b * 256 + t;
        float4 f = ((const float4*)x)[i];
        ushort4v o = { f2bf(f.x), f2bf(f.y), f2bf(f.z), f2bf(f.w) };
        ((ushort4v*)xb)[i] = o;
        return;
    }
    if (b >= 3072) {                // hub bitmask: 32 tiles of 64 tokens
        if (t < NTOK / 64) {
            u64 m = 0;
            for (int j = 0; j < 64; ++j)
                m |= (u64)(is_hub[t * 64 + j] != 0) << j;
            hubmask[t] = m;
        }
        return;
    }

    const float* W; ushort* WT; int K, N, n0, k0;
    if (b < 2816) { int idx = b - 2048; W = Wqkv;  WT = wqkvT;  K = 1024; N = 3072;
                    n0 = (idx % 48) * 64; k0 = (idx / 48) * 64; }
    else          { int idx = b - 2816; W = Wproj; WT = wprojT; K = 1024; N = 1024;
                    n0 = (idx & 15) * 64; k0 = (idx >> 4) * 64; }

    const int kr = t >> 4, nc = t & 15;
#pragma unroll
    for (int i = 0; i < 4; ++i) {
        int k = kr + i * 16;
        float4 w4 = *(const float4*)(W + (size_t)(k0 + k) * N + n0 + nc * 4);
        LT[nc*4+0][k] = f2bf(w4.x);
        LT[nc*4+1][k] = f2bf(w4.y);
        LT[nc*4+2][k] = f2bf(w4.z);
        LT[nc*4+3][k] = f2bf(w4.w);
    }
    __syncthreads();
    const int n = t >> 2;
#pragma unroll
    for (int half = 0; half < 2; ++half) {
        int kc = (t & 3) + 4 * half;
        ushort8 v = *(const ushort8*)&LT[n][kc * 8];
        *(ushort8*)(WT + (size_t)(n0 + n) * K + k0 + kc * 8) = v;
    }
}

// ---------------------------------------------------------------------------
// bf16 MFMA GEMM: C = A[M,K] @ BT[N,K]^T + bias
// 128(M) x 64(N) tile, 4 waves (each 32 rows x 64 cols), BK=32, dbuf staging.
// R12: retiled from 128x128 for grid balance — QKV 384->768 blocks (3/CU
// exact), proj 128->256 blocks (was HALF THE CHIP IDLE, now 1/CU exact).
// mode 0: fp32 store [M][N];  mode 1: Q,K -> qkvb [2][H][N][D]; V -> vTb
// (per-block uniform part/head since TN=64 == head dim).
// ---------------------------------------------------------------------------
__global__ __launch_bounds__(256)
void gemm_bt_kernel(const ushort* __restrict__ A, const ushort* __restrict__ BT,
                    const float* __restrict__ bias, void* __restrict__ out,
                    ushort* __restrict__ vtb,
                    int M, int N, int K, int mode)
{
    __shared__ ushort As[2][128 * 32];
    __shared__ ushort Bs[2][64 * 32];

    const int t = threadIdx.x;
    const int wave = t >> 6, lane = t & 63;
    const int quad = lane >> 4, l15 = lane & 15;
    const int row0 = blockIdx.y * 128, col0 = blockIdx.x * 64;
    const int wm = wave * 32;

    const int sr = lane >> 2;         // row within a 16-row staging group
    const int sc = (lane & 3) * 8;    // ushort offset (16B chunks)
    const int rb = wave * 16;         // B staging rows per wave

    floatx4 acc[2][4];
#pragma unroll
    for (int i = 0; i < 2; ++i)
#pragma unroll
        for (int j = 0; j < 4; ++j) acc[i][j] = (floatx4){0.f, 0.f, 0.f, 0.f};

    gload_lds16(A  + (size_t)(row0 + wm      + sr) * K + sc, &As[0][ wm       * 32]);
    gload_lds16(A  + (size_t)(row0 + wm + 16 + sr) * K + sc, &As[0][(wm + 16) * 32]);
    gload_lds16(BT + (size_t)(col0 + rb      + sr) * K + sc, &Bs[0][ rb       * 32]);

    const int nk = K >> 5;
    for (int ki = 0; ki < nk; ++ki) {
        __syncthreads();   // buf[ki&1] staged; all waves done reading buf[(ki+1)&1]
        if (ki + 1 < nk) {
            const int kn = (ki + 1) << 5;
            const int b = (ki + 1) & 1;
            gload_lds16(A  + (size_t)(row0 + wm      + sr) * K + kn + sc, &As[b][ wm       * 32]);
            gload_lds16(A  + (size_t)(row0 + wm + 16 + sr) * K + kn + sc, &As[b][(wm + 16) * 32]);
            gload_lds16(BT + (size_t)(col0 + rb      + sr) * K + kn + sc, &Bs[b][ rb       * 32]);
        }
        const ushort* as = As[ki & 1];
        const ushort* bs = Bs[ki & 1];

        short8 af[2], bfr[4];
#pragma unroll
        for (int i = 0; i < 2; ++i)
            af[i] = *(const short8*)&as[(wm + i * 16 + l15) * 32 + quad * 8];
#pragma unroll
        for (int j = 0; j < 4; ++j)
            bfr[j] = *(const short8*)&bs[(j * 16 + l15) * 32 + quad * 8];
#pragma unroll
        for (int i = 0; i < 2; ++i)
#pragma unroll
            for (int j = 0; j < 4; ++j)
                acc[i][j] = __builtin_amdgcn_mfma_f32_16x16x32_bf16(af[i], bfr[j], acc[i][j], 0, 0, 0);
    }

    if (mode == 0) {
        float* outf = (float*)out;
#pragma unroll
        for (int j = 0; j < 4; ++j) {
            int col = col0 + j * 16 + l15;
            float bb = bias[col];
#pragma unroll
            for (int i = 0; i < 2; ++i) {
                int rowb = row0 + wm + i * 16 + quad * 4;
#pragma unroll
                for (int r = 0; r < 4; ++r)
                    outf[(size_t)(rowb + r) * N + col] = acc[i][j][r] + bb;
            }
        }
    } else {
        // block-uniform: whole 64-col tile is one (part, head)
        const int part = col0 >> 10, hh = (col0 >> 6) & 15;
        if (part < 2) {        // Q,K -> [part][H][N][D]
            ushort* dst = (ushort*)out + ((size_t)(part * NHEAD + hh) * NTOK) * HDIM;
#pragma unroll
            for (int j = 0; j < 4; ++j) {
                int d = j * 16 + l15;
                float bb = bias[col0 + j * 16 + l15];
#pragma unroll
                for (int i = 0; i < 2; ++i) {
                    int rowb = row0 + wm + i * 16 + quad * 4;
#pragma unroll
                    for (int r = 0; r < 4; ++r)
                        dst[(size_t)(rowb + r) * HDIM + d] = f2bf(acc[i][j][r] + bb);
                }
            }
        } else {               // V -> vT [H][D][N] (fused transpose)
#pragma unroll
            for (int j = 0; j < 4; ++j) {
                int d = j * 16 + l15;
                float bb = bias[col0 + j * 16 + l15];
                ushort* dst = vtb + ((size_t)hh * HDIM + d) * NTOK;
#pragma unroll
                for (int i = 0; i < 2; ++i) {
                    int rowb = row0 + wm + i * 16 + quad * 4;
#pragma unroll
                    for (int r = 0; r < 4; ++r)
                        dst[rowb + r] = f2bf(acc[i][j][r] + bb);
                }
            }
        }
    }
}

// ---------------------------------------------------------------------------
// Staged MFMA flash attention (R11-validated): block = (head, 64-q tile),
// 4 waves. Coalesced 1KB/instr staging, +72 padded rows (2-way max bank
// conflicts), double-buffered (prefetch flies one compute phase), no-max
// softmax, XCD-locked heads, hubmask bit-tests.
// ---------------------------------------------------------------------------
__global__ __launch_bounds__(256)
void attn_tile_kernel(const ushort* __restrict__ qkvb,   // [2][H][N][D] bf16 (Q,K)
                      const ushort* __restrict__ vTb,    // [H][D][N] bf16
                      const int* __restrict__ frame_ids,
                      const u64* __restrict__ hubmask,   // [NTOK/64]
                      const int* __restrict__ adj,
                      const float* __restrict__ frame_bias,
                      ushort* __restrict__ attnb)        // [N][C] bf16
{
    __shared__ ushort Ks [2][64 * 72];   // K  tile [key][d], padded
    __shared__ ushort VTs[2][64 * 72];   // V^T tile [d][key], padded
    __shared__ ushort Ps [4][16 * 72];   // per-wave P strip

    const int t = threadIdx.x;
    const int wave = t >> 6, lane = t & 63;
    const int quad = lane >> 4, l15 = lane & 15;
    const int b = blockIdx.x;
    const int h = b & 15, q0 = (b >> 4) * 64;   // XCD-locking swizzle

    const ushort* Qg = qkvb + ((size_t)h * NTOK) * HDIM;
    const ushort* Kg = qkvb + ((size_t)(NHEAD + h) * NTOK) * HDIM;
    const ushort* Vg = vTb + ((size_t)h * HDIM) * NTOK;

    // Q A-frags in registers (wave owns q rows q0+wave*16 .. +16)
    short8 aq0 = *(const short8*)(Qg + (size_t)(q0 + wave * 16 + l15) * HDIM + quad * 8);
    short8 aq1 = *(const short8*)(Qg + (size_t)(q0 + wave * 16 + l15) * HDIM + 32 + quad * 8);

    // packed visible-frame list (uniform)
    const int fq = frame_ids[q0];
    unsigned vpack = 0; int nv = 0;
#pragma unroll
    for (int f = 0; f < NFRM; ++f)
        if (adj[fq * NFRM + f]) { vpack |= (unsigned)f << (3 * nv); ++nv; }
    const int ntot = nv * 4;

    const u64 hmq = hubmask[q0 >> 6];
    int qh[4];
#pragma unroll
    for (int r = 0; r < 4; ++r) qh[r] = (int)((hmq >> (wave * 16 + quad * 4 + r)) & 1);

    float lpart[4] = {0.f, 0.f, 0.f, 0.f};
    floatx4 oacc[4];
#pragma unroll
    for (int dt = 0; dt < 4; ++dt) oacc[dt] = (floatx4){0.f, 0.f, 0.f, 0.f};

    // staging: wave stages rows [wave*16, +16); 1KB contiguous per ushort8 op
    const int sro = wave * 16 + (lane >> 3);
    const int sc  = (lane & 7) * 8;

    auto tile_k0 = [&](int vt) -> int {
        const int fj = (int)((vpack >> (3 * (vt >> 2))) & 7u);
        return fj * FTOK + (vt & 3) * 64;
    };

    auto stage = [&](int vt) {
        const int k0 = tile_k0(vt);
        const int bf = vt & 1;
        ushort8 k8a = *(const ushort8*)(Kg + (size_t)(k0 + sro)     * HDIM + sc);
        ushort8 k8b = *(const ushort8*)(Kg + (size_t)(k0 + sro + 8) * HDIM + sc);
        ushort8 v8a = *(const ushort8*)(Vg + (size_t)(sro)     * NTOK + k0 + sc);
        ushort8 v8b = *(const ushort8*)(Vg + (size_t)(sro + 8) * NTOK + k0 + sc);
        *(ushort8*)&Ks [bf][ sro      * 72 + sc] = k8a;
        *(ushort8*)&Ks [bf][(sro + 8) * 72 + sc] = k8b;
        *(ushort8*)&VTs[bf][ sro      * 72 + sc] = v8a;
        *(ushort8*)&VTs[bf][(sro + 8) * 72 + sc] = v8b;
    };

    stage(0);

    for (int vt = 0; vt < ntot; ++vt) {
        __syncthreads();   // buf[vt&1] staged; buf[(vt+1)&1] free

        if (vt + 1 < ntot) stage(vt + 1);   // prefetch flies across this compute

        const int fj = (int)((vpack >> (3 * (vt >> 2))) & 7u);
        const int k0 = fj * FTOK + (vt & 3) * 64;
        const float fb = frame_bias[fq * NFRM + fj];
        const bool same = (fj == fq);
        const u64 hmk = hubmask[k0 >> 6];
        const ushort* ks = Ks[vt & 1];
        const ushort* vs = VTs[vt & 1];

        // S strip [16 q][64 keys] = Q @ K^T
        floatx4 s[4];
#pragma unroll
        for (int nt = 0; nt < 4; ++nt) {
            short8 bk0 = *(const short8*)&ks[(nt * 16 + l15) * 72 + quad * 8];
            short8 bk1 = *(const short8*)&ks[(nt * 16 + l15) * 72 + 32 + quad * 8];
            s[nt] = (floatx4){0.f, 0.f, 0.f, 0.f};
            s[nt] = __builtin_amdgcn_mfma_f32_16x16x32_bf16(aq0, bk0, s[nt], 0, 0, 0);
            s[nt] = __builtin_amdgcn_mfma_f32_16x16x32_bf16(aq1, bk1, s[nt], 0, 0, 0);
        }

        // mask + scale + bias + exp (no max, no cross-lane); P -> LDS strip
#pragma unroll
        for (int r = 0; r < 4; ++r) {
            float ps = 0.f;
#pragma unroll
            for (int nt = 0; nt < 4; ++nt) {
                int kh = (int)((hmk >> (nt * 16 + l15)) & 1);
                bool allow = same || ((qh[r] == 0) && (kh == 0));
                float sv = allow ? fmaf(s[nt][r], 0.125f, fb) : -1.0e30f;
                float p = __expf(sv);          // exp(-1e30) = 0 exactly
                ps += p;
                Ps[wave][(quad * 4 + r) * 72 + nt * 16 + l15] = f2bf(p);
            }
            lpart[r] += ps;
        }

        // O strip += P @ V  (wave-private P; V^T from padded LDS)
        short8 ap0 = *(const short8*)&Ps[wave][l15 * 72 + quad * 8];
        short8 ap1 = *(const short8*)&Ps[wave][l15 * 72 + 32 + quad * 8];
#pragma unroll
        for (int dt = 0; dt < 4; ++dt) {
            short8 bv0 = *(const short8*)&vs[(dt * 16 + l15) * 72 + quad * 8];
            short8 bv1 = *(const short8*)&vs[(dt * 16 + l15) * 72 + 32 + quad * 8];
            oacc[dt] = __builtin_amdgcn_mfma_f32_16x16x32_bf16(ap0, bv0, oacc[dt], 0, 0, 0);
            oacc[dt] = __builtin_amdgcn_mfma_f32_16x16x32_bf16(ap1, bv1, oacc[dt], 0, 0, 0);
        }
    }

    // final row-sum reduction across the 16 l15 lanes (once per kernel)
    float linv[4];
#pragma unroll
    for (int r = 0; r < 4; ++r) {
        float ls = lpart[r];
        ls += __shfl_xor(ls, 1);
        ls += __shfl_xor(ls, 2);
        ls += __shfl_xor(ls, 4);
        ls += __shfl_xor(ls, 8);
        linv[r] = 1.0f / ls;
    }

    // epilogue: attnb[row][h*64 + d] bf16
#pragma unroll
    for (int dt = 0; dt < 4; ++dt) {
        int col = h * HDIM + dt * 16 + l15;
#pragma unroll
        for (int r = 0; r < 4; ++r) {
            int row = q0 + wave * 16 + quad * 4 + r;
            attnb[(size_t)row * CDIM + col] = f2bf(oacc[dt][r] * linv[r]);
        }
    }
}

// ---------------------------------------------------------------------------
extern "C" void kernel_launch(void* const* d_in, const int* in_sizes, int n_in,
                              void* d_out, int out_size, void* d_ws, size_t ws_size,
                              hipStream_t stream)
{
    const float* x          = (const float*)d_in[0];
    const int*   frame_ids  = (const int*)d_in[1];
    const int*   is_hub     = (const int*)d_in[2];
    const int*   adj        = (const int*)d_in[3];
    const float* frame_bias = (const float*)d_in[4];
    const float* Wqkv       = (const float*)d_in[5];
    const float* bqkv       = (const float*)d_in[6];
    const float* Wproj      = (const float*)d_in[7];
    const float* bproj      = (const float*)d_in[8];
    float* out = (float*)d_out;

    // workspace layout (ushort units)
    ushort* xb     = (ushort*)d_ws;            // 2048*1024
    ushort* wqkvT  = xb     + 2097152;         // 3072*1024
    ushort* wprojT = wqkvT  + 3145728;         // 1024*1024
    ushort* qkvb   = wprojT + 1048576;         // [2][H][N][D] used
    ushort* vTb    = qkvb   + 6291456;         // 16*64*2048
    ushort* attnb  = vTb    + 2097152;         // 2048*1024
    u64*    hubmask = (u64*)(attnb + 2097152); // 32 x u64

    prep_kernel<<<dim3(3073), dim3(256), 0, stream>>>(
        x, xb, Wqkv, wqkvT, Wproj, wprojT, is_hub, hubmask);

    // QKV: [2048,1024] @ [1024,3072]; Q,K -> qkvb, V -> vTb (fused transpose)
    // grid 48 x 16 = 768 blocks = exactly 3/CU
    gemm_bt_kernel<<<dim3(3 * CDIM / 64, NTOK / 128), dim3(256), 0, stream>>>(
        xb, wqkvT, bqkv, qkvb, vTb, NTOK, 3 * CDIM, CDIM, 1);

    attn_tile_kernel<<<dim3(512), dim3(256), 0, stream>>>(
        qkvb, vTb, frame_ids, hubmask, adj, frame_bias, attnb);

    // proj: [2048,1024] @ [1024,1024] -> fp32 d_out
    // grid 16 x 16 = 256 blocks = exactly 1/CU (was 128 = half chip idle)
    gemm_bt_kernel<<<dim3(CDIM / 64, NTOK / 128), dim3(256), 0, stream>>>(
        attnb, wprojT, bproj, out, nullptr, NTOK, CDIM, CDIM, 0);
}

// Round 14
// 155.944 us; speedup vs baseline: 1.0076x; 1.0076x over previous
//
#include <hip/hip_runtime.h>
#include <hip/hip_cooperative_groups.h>

namespace cg = cooperative_groups;

#define NTOK 2048
#define CDIM 1024
#define NHEAD 16
#define HDIM 64
#define NFRM 8
#define FTOK 256

typedef unsigned short ushort;
typedef unsigned long long u64;
typedef __attribute__((ext_vector_type(8))) short short8;     // 8 bf16 = 4 VGPRs (MFMA A/B frag)
typedef __attribute__((ext_vector_type(8))) ushort ushort8;
typedef __attribute__((ext_vector_type(4))) ushort ushort4v;
typedef __attribute__((ext_vector_type(4))) float floatx4;    // MFMA C/D frag

__device__ __forceinline__ ushort f2bf(float f) {
    unsigned int u = __float_as_uint(f);
    return (ushort)((u + 0x7fffu + ((u >> 16) & 1u)) >> 16);   // RNE
}

// async global->LDS, 16B per lane; LDS dest = wave-uniform base + lane*16
__device__ __forceinline__ void gload_lds16(const void* g, void* l) {
    __builtin_amdgcn_global_load_lds(
        (const __attribute__((address_space(1))) unsigned int*)(uintptr_t)g,
        (__attribute__((address_space(3))) unsigned int*)(unsigned int)(uintptr_t)l,
        16, 0, 0);
}

// ===========================================================================
// FALLBACK PATH — exact R11 kernels (validated: 154.3 us total)
// ===========================================================================

__global__ __launch_bounds__(256)
void prep_kernel(const float* __restrict__ x, ushort* __restrict__ xb,
                 const float* __restrict__ Wqkv, ushort* __restrict__ wqkvT,
                 const float* __restrict__ Wproj, ushort* __restrict__ wprojT,
                 const int* __restrict__ is_hub, u64* __restrict__ hubmask)
{
    __shared__ ushort LT[64][72];
    const int b = blockIdx.x, t = threadIdx.x;

    if (b < 2048) {
        int i = b * 256 + t;
        float4 f = ((const float4*)x)[i];
        ushort4v o = { f2bf(f.x), f2bf(f.y), f2bf(f.z), f2bf(f.w) };
        ((ushort4v*)xb)[i] = o;
        return;
    }
    if (b >= 3072) {
        if (t < NTOK / 64) {
            u64 m = 0;
            for (int j = 0; j < 64; ++j)
                m |= (u64)(is_hub[t * 64 + j] != 0) << j;
            hubmask[t] = m;
        }
        return;
    }

    const float* W; ushort* WT; int K, N, n0, k0;
    if (b < 2816) { int idx = b - 2048; W = Wqkv;  WT = wqkvT;  K = 1024; N = 3072;
                    n0 = (idx % 48) * 64; k0 = (idx / 48) * 64; }
    else          { int idx = b - 2816; W = Wproj; WT = wprojT; K = 1024; N = 1024;
                    n0 = (idx & 15) * 64; k0 = (idx >> 4) * 64; }

    const int kr = t >> 4, nc = t & 15;
#pragma unroll
    for (int i = 0; i < 4; ++i) {
        int k = kr + i * 16;
        float4 w4 = *(const float4*)(W + (size_t)(k0 + k) * N + n0 + nc * 4);
        LT[nc*4+0][k] = f2bf(w4.x);
        LT[nc*4+1][k] = f2bf(w4.y);
        LT[nc*4+2][k] = f2bf(w4.z);
        LT[nc*4+3][k] = f2bf(w4.w);
    }
    __syncthreads();
    const int n = t >> 2;
#pragma unroll
    for (int half = 0; half < 2; ++half) {
        int kc = (t & 3) + 4 * half;
        ushort8 v = *(const ushort8*)&LT[n][kc * 8];
        *(ushort8*)(WT + (size_t)(n0 + n) * K + k0 + kc * 8) = v;
    }
}

__global__ __launch_bounds__(256)
void gemm_bt_kernel(const ushort* __restrict__ A, const ushort* __restrict__ BT,
                    const float* __restrict__ bias, void* __restrict__ out,
                    ushort* __restrict__ vtb,
                    int M, int N, int K, int mode)
{
    __shared__ ushort As[2][128 * 32];
    __shared__ ushort Bs[2][128 * 32];

    const int t = threadIdx.x;
    const int wave = t >> 6, lane = t & 63;
    const int quad = lane >> 4, l15 = lane & 15;
    const int row0 = blockIdx.y * 128, col0 = blockIdx.x * 128;
    const int wm = (wave >> 1) * 64, wn = (wave & 1) * 64;

    const int sr = lane >> 2, sc = (lane & 3) * 8;
    const int r0 = wave * 32;

    floatx4 acc[4][4];
#pragma unroll
    for (int i = 0; i < 4; ++i)
#pragma unroll
        for (int j = 0; j < 4; ++j) acc[i][j] = (floatx4){0.f, 0.f, 0.f, 0.f};

    gload_lds16(A  + (size_t)(row0 + r0      + sr) * K + sc, &As[0][ r0       * 32]);
    gload_lds16(A  + (size_t)(row0 + r0 + 16 + sr) * K + sc, &As[0][(r0 + 16) * 32]);
    gload_lds16(BT + (size_t)(col0 + r0      + sr) * K + sc, &Bs[0][ r0       * 32]);
    gload_lds16(BT + (size_t)(col0 + r0 + 16 + sr) * K + sc, &Bs[0][(r0 + 16) * 32]);

    const int nk = K >> 5;
    for (int ki = 0; ki < nk; ++ki) {
        __syncthreads();
        if (ki + 1 < nk) {
            const int kn = (ki + 1) << 5;
            const int b = (ki + 1) & 1;
            gload_lds16(A  + (size_t)(row0 + r0      + sr) * K + kn + sc, &As[b][ r0       * 32]);
            gload_lds16(A  + (size_t)(row0 + r0 + 16 + sr) * K + kn + sc, &As[b][(r0 + 16) * 32]);
            gload_lds16(BT + (size_t)(col0 + r0      + sr) * K + kn + sc, &Bs[b][ r0       * 32]);
            gload_lds16(BT + (size_t)(col0 + r0 + 16 + sr) * K + kn + sc, &Bs[b][(r0 + 16) * 32]);
        }
        const ushort* as = As[ki & 1];
        const ushort* bs = Bs[ki & 1];

        short8 af[4], bfr[4];
#pragma unroll
        for (int i = 0; i < 4; ++i)
            af[i] = *(const short8*)&as[(wm + i * 16 + l15) * 32 + quad * 8];
#pragma unroll
        for (int j = 0; j < 4; ++j)
            bfr[j] = *(const short8*)&bs[(wn + j * 16 + l15) * 32 + quad * 8];
#pragma unroll
        for (int i = 0; i < 4; ++i)
#pragma unroll
            for (int j = 0; j < 4; ++j)
                acc[i][j] = __builtin_amdgcn_mfma_f32_16x16x32_bf16(af[i], bfr[j], acc[i][j], 0, 0, 0);
    }

    if (mode == 0) {
        float* outf = (float*)out;
#pragma unroll
        for (int j = 0; j < 4; ++j) {
            int col = col0 + wn + j * 16 + l15;
            float bb = bias[col];
#pragma unroll
            for (int i = 0; i < 4; ++i) {
                int rowb = row0 + wm + i * 16 + quad * 4;
#pragma unroll
                for (int r = 0; r < 4; ++r)
                    outf[(size_t)(rowb + r) * N + col] = acc[i][j][r] + bb;
            }
        }
    } else {
        ushort* outb = (ushort*)out;
#pragma unroll
        for (int j = 0; j < 4; ++j) {
            int col = col0 + wn + j * 16 + l15;
            float bb = bias[col];
            int part = col >> 10, hh = (col >> 6) & 15, d = col & 63;
            if (part < 2) {
                ushort* dst = outb + ((size_t)(part * NHEAD + hh) * NTOK) * HDIM + d;
#pragma unroll
                for (int i = 0; i < 4; ++i) {
                    int rowb = row0 + wm + i * 16 + quad * 4;
#pragma unroll
                    for (int r = 0; r < 4; ++r)
                        dst[(size_t)(rowb + r) * HDIM] = f2bf(acc[i][j][r] + bb);
                }
            } else {
                ushort* dst = vtb + ((size_t)hh * HDIM + d) * NTOK;
#pragma unroll
                for (int i = 0; i < 4; ++i) {
                    int rowb = row0 + wm + i * 16 + quad * 4;
#pragma unroll
                    for (int r = 0; r < 4; ++r)
                        dst[rowb + r] = f2bf(acc[i][j][r] + bb);
                }
            }
        }
    }
}

__global__ __launch_bounds__(256)
void attn_tile_kernel(const ushort* __restrict__ qkvb,
                      const ushort* __restrict__ vTb,
                      const int* __restrict__ frame_ids,
                      const u64* __restrict__ hubmask,
                      const int* __restrict__ adj,
                      const float* __restrict__ frame_bias,
                      ushort* __restrict__ attnb)
{
    __shared__ ushort Ks [2][64 * 72];
    __shared__ ushort VTs[2][64 * 72];
    __shared__ ushort Ps [4][16 * 72];

    const int t = threadIdx.x;
    const int wave = t >> 6, lane = t & 63;
    const int quad = lane >> 4, l15 = lane & 15;
    const int b = blockIdx.x;
    const int h = b & 15, q0 = (b >> 4) * 64;

    const ushort* Qg = qkvb + ((size_t)h * NTOK) * HDIM;
    const ushort* Kg = qkvb + ((size_t)(NHEAD + h) * NTOK) * HDIM;
    const ushort* Vg = vTb + ((size_t)h * HDIM) * NTOK;

    short8 aq0 = *(const short8*)(Qg + (size_t)(q0 + wave * 16 + l15) * HDIM + quad * 8);
    short8 aq1 = *(const short8*)(Qg + (size_t)(q0 + wave * 16 + l15) * HDIM + 32 + quad * 8);

    const int fq = frame_ids[q0];
    unsigned vpack = 0; int nv = 0;
#pragma unroll
    for (int f = 0; f < NFRM; ++f)
        if (adj[fq * NFRM + f]) { vpack |= (unsigned)f << (3 * nv); ++nv; }
    const int ntot = nv * 4;

    const u64 hmq = hubmask[q0 >> 6];
    int qh[4];
#pragma unroll
    for (int r = 0; r < 4; ++r) qh[r] = (int)((hmq >> (wave * 16 + quad * 4 + r)) & 1);

    float lpart[4] = {0.f, 0.f, 0.f, 0.f};
    floatx4 oacc[4];
#pragma unroll
    for (int dt = 0; dt < 4; ++dt) oacc[dt] = (floatx4){0.f, 0.f, 0.f, 0.f};

    const int sro = wave * 16 + (lane >> 3);
    const int sc  = (lane & 7) * 8;

    auto tile_k0 = [&](int vt) -> int {
        const int fj = (int)((vpack >> (3 * (vt >> 2))) & 7u);
        return fj * FTOK + (vt & 3) * 64;
    };

    auto stage = [&](int vt) {
        const int k0 = tile_k0(vt);
        const int bf = vt & 1;
        ushort8 k8a = *(const ushort8*)(Kg + (size_t)(k0 + sro)     * HDIM + sc);
        ushort8 k8b = *(const ushort8*)(Kg + (size_t)(k0 + sro + 8) * HDIM + sc);
        ushort8 v8a = *(const ushort8*)(Vg + (size_t)(sro)     * NTOK + k0 + sc);
        ushort8 v8b = *(const ushort8*)(Vg + (size_t)(sro + 8) * NTOK + k0 + sc);
        *(ushort8*)&Ks [bf][ sro      * 72 + sc] = k8a;
        *(ushort8*)&Ks [bf][(sro + 8) * 72 + sc] = k8b;
        *(ushort8*)&VTs[bf][ sro      * 72 + sc] = v8a;
        *(ushort8*)&VTs[bf][(sro + 8) * 72 + sc] = v8b;
    };

    stage(0);

    for (int vt = 0; vt < ntot; ++vt) {
        __syncthreads();
        if (vt + 1 < ntot) stage(vt + 1);

        const int fj = (int)((vpack >> (3 * (vt >> 2))) & 7u);
        const int k0 = fj * FTOK + (vt & 3) * 64;
        const float fb = frame_bias[fq * NFRM + fj];
        const bool same = (fj == fq);
        const u64 hmk = hubmask[k0 >> 6];
        const ushort* ks = Ks[vt & 1];
        const ushort* vs = VTs[vt & 1];

        floatx4 s[4];
#pragma unroll
        for (int nt = 0; nt < 4; ++nt) {
            short8 bk0 = *(const short8*)&ks[(nt * 16 + l15) * 72 + quad * 8];
            short8 bk1 = *(const short8*)&ks[(nt * 16 + l15) * 72 + 32 + quad * 8];
            s[nt] = (floatx4){0.f, 0.f, 0.f, 0.f};
            s[nt] = __builtin_amdgcn_mfma_f32_16x16x32_bf16(aq0, bk0, s[nt], 0, 0, 0);
            s[nt] = __builtin_amdgcn_mfma_f32_16x16x32_bf16(aq1, bk1, s[nt], 0, 0, 0);
        }

#pragma unroll
        for (int r = 0; r < 4; ++r) {
            float ps = 0.f;
#pragma unroll
            for (int nt = 0; nt < 4; ++nt) {
                int kh = (int)((hmk >> (nt * 16 + l15)) & 1);
                bool allow = same || ((qh[r] == 0) && (kh == 0));
                float sv = allow ? fmaf(s[nt][r], 0.125f, fb) : -1.0e30f;
                float p = __expf(sv);
                ps += p;
                Ps[wave][(quad * 4 + r) * 72 + nt * 16 + l15] = f2bf(p);
            }
            lpart[r] += ps;
        }

        short8 ap0 = *(const short8*)&Ps[wave][l15 * 72 + quad * 8];
        short8 ap1 = *(const short8*)&Ps[wave][l15 * 72 + 32 + quad * 8];
#pragma unroll
        for (int dt = 0; dt < 4; ++dt) {
            short8 bv0 = *(const short8*)&vs[(dt * 16 + l15) * 72 + quad * 8];
            short8 bv1 = *(const short8*)&vs[(dt * 16 + l15) * 72 + 32 + quad * 8];
            oacc[dt] = __builtin_amdgcn_mfma_f32_16x16x32_bf16(ap0, bv0, oacc[dt], 0, 0, 0);
            oacc[dt] = __builtin_amdgcn_mfma_f32_16x16x32_bf16(ap1, bv1, oacc[dt], 0, 0, 0);
        }
    }

    float linv[4];
#pragma unroll
    for (int r = 0; r < 4; ++r) {
        float ls = lpart[r];
        ls += __shfl_xor(ls, 1);
        ls += __shfl_xor(ls, 2);
        ls += __shfl_xor(ls, 4);
        ls += __shfl_xor(ls, 8);
        linv[r] = 1.0f / ls;
    }

#pragma unroll
    for (int dt = 0; dt < 4; ++dt) {
        int col = h * HDIM + dt * 16 + l15;
#pragma unroll
        for (int r = 0; r < 4; ++r) {
            int row = q0 + wave * 16 + quad * 4 + r;
            attnb[(size_t)row * CDIM + col] = f2bf(oacc[dt][r] * linv[r]);
        }
    }
}

// ===========================================================================
// COOPERATIVE PATH — one fused kernel, 512 blocks x 256 threads, LDS 28.6 KB
// (<= 32 KB so even a conservative 64 KB/CU occupancy model gives 2 blocks/CU
//  -> 512 co-resident). Attn phase stages K only (dbuf, padded); V is direct
//  register B-frags issued right after the barrier (softmax of slack).
// ===========================================================================

struct KParams {
    const float* x; const int* frame_ids; const int* is_hub; const int* adj;
    const float* frame_bias; const float* Wqkv; const float* bqkv;
    const float* Wproj; const float* bproj; float* out;
    ushort* xb; ushort* wqkvT; ushort* wprojT;
    ushort* qkvb; ushort* vTb; ushort* attnb; u64* hubmask;
};

__global__ __launch_bounds__(256)
void fused_kernel(KParams p)
{
    __shared__ ushort SH[14336];   // 28672 B, unioned across phases
    cg::grid_group grid = cg::this_grid();

    const int t = threadIdx.x;
    const int wave = t >> 6, lane = t & 63;
    const int quad = lane >> 4, l15 = lane & 15;

    // ---------- phase 0: prep ----------
    for (int u = blockIdx.x; u < 3073; u += 512) {
        if (u < 2048) {
            int i = u * 256 + t;
            float4 f = ((const float4*)p.x)[i];
            ushort4v o = { f2bf(f.x), f2bf(f.y), f2bf(f.z), f2bf(f.w) };
            ((ushort4v*)p.xb)[i] = o;
        } else if (u == 3072) {
            if (t < NTOK / 64) {
                u64 m = 0;
                for (int j = 0; j < 64; ++j)
                    m |= (u64)(p.is_hub[t * 64 + j] != 0) << j;
                p.hubmask[t] = m;
            }
        } else {
            ushort (*LT)[72] = (ushort(*)[72])SH;
            const float* W; ushort* WT; int K, N, n0, k0;
            if (u < 2816) { int idx = u - 2048; W = p.Wqkv;  WT = p.wqkvT;  K = 1024; N = 3072;
                            n0 = (idx % 48) * 64; k0 = (idx / 48) * 64; }
            else          { int idx = u - 2816; W = p.Wproj; WT = p.wprojT; K = 1024; N = 1024;
                            n0 = (idx & 15) * 64; k0 = (idx >> 4) * 64; }
            __syncthreads();
            const int kr = t >> 4, nc = t & 15;
#pragma unroll
            for (int i2 = 0; i2 < 4; ++i2) {
                int k = kr + i2 * 16;
                float4 w4 = *(const float4*)(W + (size_t)(k0 + k) * N + n0 + nc * 4);
                LT[nc*4+0][k] = f2bf(w4.x);
                LT[nc*4+1][k] = f2bf(w4.y);
                LT[nc*4+2][k] = f2bf(w4.z);
                LT[nc*4+3][k] = f2bf(w4.w);
            }
            __syncthreads();
            const int n = t >> 2;
#pragma unroll
            for (int half = 0; half < 2; ++half) {
                int kc = (t & 3) + 4 * half;
                ushort8 v = *(const ushort8*)&LT[n][kc * 8];
                *(ushort8*)(WT + (size_t)(n0 + n) * K + k0 + kc * 8) = v;
            }
        }
    }
    grid.sync();

    // ---------- phase 1: QKV GEMM 128x96 (512 tiles exact) ----------
    {
        const int bx = blockIdx.x & 31, by = blockIdx.x >> 5;   // 32 x 16
        const int row0 = by * 128, col0 = bx * 96;
        const ushort* A  = p.xb;
        const ushort* BT = p.wqkvT;
        ushort* As = SH;             // 2 x 4096 ushorts
        ushort* Bs = SH + 8192;      // 2 x 3072 ushorts
        const int K = 1024;
        const int sr = lane >> 2, sc = (lane & 3) * 8;
        const int wm = (wave >> 1) * 64, wn = (wave & 1) * 48;

        floatx4 acc[4][3];
#pragma unroll
        for (int i = 0; i < 4; ++i)
#pragma unroll
            for (int j = 0; j < 3; ++j) acc[i][j] = (floatx4){0.f, 0.f, 0.f, 0.f};

        auto stage = [&](int buf, int kk) {
            ushort* as = As + buf * 4096;
            ushort* bs = Bs + buf * 3072;
            for (int g = wave; g < 8; g += 4)
                gload_lds16(A  + (size_t)(row0 + g * 16 + sr) * K + kk + sc, &as[(g * 16) * 32]);
            for (int g = wave; g < 6; g += 4)
                gload_lds16(BT + (size_t)(col0 + g * 16 + sr) * K + kk + sc, &bs[(g * 16) * 32]);
        };
        stage(0, 0);

        for (int ki = 0; ki < 32; ++ki) {
            __syncthreads();
            if (ki + 1 < 32) stage((ki + 1) & 1, (ki + 1) << 5);
            const ushort* as = As + (ki & 1) * 4096;
            const ushort* bs = Bs + (ki & 1) * 3072;

            short8 af[4], bfr[3];
#pragma unroll
            for (int i = 0; i < 4; ++i)
                af[i] = *(const short8*)&as[(wm + i * 16 + l15) * 32 + quad * 8];
#pragma unroll
            for (int j = 0; j < 3; ++j)
                bfr[j] = *(const short8*)&bs[(wn + j * 16 + l15) * 32 + quad * 8];
#pragma unroll
            for (int i = 0; i < 4; ++i)
#pragma unroll
                for (int j = 0; j < 3; ++j)
                    acc[i][j] = __builtin_amdgcn_mfma_f32_16x16x32_bf16(af[i], bfr[j], acc[i][j], 0, 0, 0);
        }

#pragma unroll
        for (int j = 0; j < 3; ++j) {
            const int colb = col0 + wn + j * 16;     // 16-aligned
            const float bb = p.bqkv[colb + l15];
            const int part = colb >> 10, hh = (colb >> 6) & 15, d0 = colb & 63;
            if (part < 2) {
                ushort* dst = p.qkvb + ((size_t)(part * NHEAD + hh) * NTOK) * HDIM + d0 + l15;
#pragma unroll
                for (int i = 0; i < 4; ++i) {
                    int rowb = row0 + wm + i * 16 + quad * 4;
#pragma unroll
                    for (int r = 0; r < 4; ++r)
                        dst[(size_t)(rowb + r) * HDIM] = f2bf(acc[i][j][r] + bb);
                }
            } else {
                ushort* dst = p.vTb + ((size_t)hh * HDIM + d0 + l15) * NTOK;
#pragma unroll
                for (int i = 0; i < 4; ++i) {
                    int rowb = row0 + wm + i * 16 + quad * 4;
#pragma unroll
                    for (int r = 0; r < 4; ++r)
                        dst[rowb + r] = f2bf(acc[i][j][r] + bb);
                }
            }
        }
    }
    grid.sync();

    // ---------- phase 2: attn (K staged dbuf + padded; V direct regs) ----------
    {
        ushort* Ks0 = SH;                     // 64*72
        ushort* Ks1 = SH + 4608;
        ushort* Ps  = SH + 9216 + wave * 1152;

        const int b = blockIdx.x;
        const int h = b & 15, q0 = (b >> 4) * 64;   // XCD-locking swizzle

        const ushort* Qg = p.qkvb + ((size_t)h * NTOK) * HDIM;
        const ushort* Kg = p.qkvb + ((size_t)(NHEAD + h) * NTOK) * HDIM;
        const ushort* Vg = p.vTb + ((size_t)h * HDIM) * NTOK;

        short8 aq0 = *(const short8*)(Qg + (size_t)(q0 + wave * 16 + l15) * HDIM + quad * 8);
        short8 aq1 = *(const short8*)(Qg + (size_t)(q0 + wave * 16 + l15) * HDIM + 32 + quad * 8);

        const int fq = p.frame_ids[q0];
        unsigned vpack = 0; int nv = 0;
#pragma unroll
        for (int f = 0; f < NFRM; ++f)
            if (p.adj[fq * NFRM + f]) { vpack |= (unsigned)f << (3 * nv); ++nv; }
        const int ntot = nv * 4;

        const u64 hmq = p.hubmask[q0 >> 6];
        int qh[4];
#pragma unroll
        for (int r = 0; r < 4; ++r) qh[r] = (int)((hmq >> (wave * 16 + quad * 4 + r)) & 1);

        float lpart[4] = {0.f, 0.f, 0.f, 0.f};
        floatx4 oacc[4];
#pragma unroll
        for (int dt = 0; dt < 4; ++dt) oacc[dt] = (floatx4){0.f, 0.f, 0.f, 0.f};

        const int sro = wave * 16 + (lane >> 3);
        const int scA = (lane & 7) * 8;

        auto tile_k0 = [&](int vt) -> int {
            const int fj = (int)((vpack >> (3 * (vt >> 2))) & 7u);
            return fj * FTOK + (vt & 3) * 64;
        };
        auto stageK = [&](int vt) {
            const int k0 = tile_k0(vt);
            ushort* kd = (vt & 1) ? Ks1 : Ks0;
            ushort8 k8a = *(const ushort8*)(Kg + (size_t)(k0 + sro)     * HDIM + scA);
            ushort8 k8b = *(const ushort8*)(Kg + (size_t)(k0 + sro + 8) * HDIM + scA);
            *(ushort8*)&kd[ sro      * 72 + scA] = k8a;
            *(ushort8*)&kd[(sro + 8) * 72 + scA] = k8b;
        };

        __syncthreads();   // SH free from phase 1
        stageK(0);

        for (int vt = 0; vt < ntot; ++vt) {
            __syncthreads();   // buf[vt&1] staged; buf[(vt+1)&1] free

            const int fj = (int)((vpack >> (3 * (vt >> 2))) & 7u);
            const int k0 = fj * FTOK + (vt & 3) * 64;
            const float fb = p.frame_bias[fq * NFRM + fj];
            const bool same = (fj == fq);
            const u64 hmk = p.hubmask[k0 >> 6];
            const ushort* ks = (vt & 1) ? Ks1 : Ks0;

            // V frags issued first (oldest in vmcnt queue -> done by PV time)
            short8 bv[4][2];
#pragma unroll
            for (int dt = 0; dt < 4; ++dt) {
                const ushort* vp = Vg + (size_t)(dt * 16 + l15) * NTOK + k0;
                bv[dt][0] = *(const short8*)(vp + quad * 8);
                bv[dt][1] = *(const short8*)(vp + 32 + quad * 8);
            }

            if (vt + 1 < ntot) stageK(vt + 1);   // prefetch K across this compute

            floatx4 s[4];
#pragma unroll
            for (int nt = 0; nt < 4; ++nt) {
                short8 bk0 = *(const short8*)&ks[(nt * 16 + l15) * 72 + quad * 8];
                short8 bk1 = *(const short8*)&ks[(nt * 16 + l15) * 72 + 32 + quad * 8];
                s[nt] = (floatx4){0.f, 0.f, 0.f, 0.f};
                s[nt] = __builtin_amdgcn_mfma_f32_16x16x32_bf16(aq0, bk0, s[nt], 0, 0, 0);
                s[nt] = __builtin_amdgcn_mfma_f32_16x16x32_bf16(aq1, bk1, s[nt], 0, 0, 0);
            }

#pragma unroll
            for (int r = 0; r < 4; ++r) {
                float ps = 0.f;
#pragma unroll
                for (int nt = 0; nt < 4; ++nt) {
                    int kh = (int)((hmk >> (nt * 16 + l15)) & 1);
                    bool allow = same || ((qh[r] == 0) && (kh == 0));
                    float sv = allow ? fmaf(s[nt][r], 0.125f, fb) : -1.0e30f;
                    float pv = __expf(sv);       // exp(-1e30) = 0 exactly
                    ps += pv;
                    Ps[(quad * 4 + r) * 72 + nt * 16 + l15] = f2bf(pv);
                }
                lpart[r] += ps;
            }

            short8 ap0 = *(const short8*)&Ps[l15 * 72 + quad * 8];
            short8 ap1 = *(const short8*)&Ps[l15 * 72 + 32 + quad * 8];
#pragma unroll
            for (int dt = 0; dt < 4; ++dt) {
                oacc[dt] = __builtin_amdgcn_mfma_f32_16x16x32_bf16(ap0, bv[dt][0], oacc[dt], 0, 0, 0);
                oacc[dt] = __builtin_amdgcn_mfma_f32_16x16x32_bf16(ap1, bv[dt][1], oacc[dt], 0, 0, 0);
            }
        }

        float linv[4];
#pragma unroll
        for (int r = 0; r < 4; ++r) {
            float ls = lpart[r];
            ls += __shfl_xor(ls, 1);
            ls += __shfl_xor(ls, 2);
            ls += __shfl_xor(ls, 4);
            ls += __shfl_xor(ls, 8);
            linv[r] = 1.0f / ls;
        }

#pragma unroll
        for (int dt = 0; dt < 4; ++dt) {
            int col = h * HDIM + dt * 16 + l15;
#pragma unroll
            for (int r = 0; r < 4; ++r) {
                int row = q0 + wave * 16 + quad * 4 + r;
                p.attnb[(size_t)row * CDIM + col] = f2bf(oacc[dt][r] * linv[r]);
            }
        }
    }
    grid.sync();

    // ---------- phase 3: proj GEMM 64x64 (512 tiles exact) ----------
    {
        const int bx = blockIdx.x & 15, by = blockIdx.x >> 4;   // 16 x 32
        const int row0 = by * 64, col0 = bx * 64;
        const ushort* A  = p.attnb;
        const ushort* BT = p.wprojT;
        ushort* As = SH;             // 2 x 2048 ushorts
        ushort* Bs = SH + 4096;      // 2 x 2048
        const int K = 1024;
        const int sr = lane >> 2, sc = (lane & 3) * 8;
        const int wm = (wave >> 1) * 32, wn = (wave & 1) * 32;

        floatx4 acc[2][2];
#pragma unroll
        for (int i = 0; i < 2; ++i)
#pragma unroll
            for (int j = 0; j < 2; ++j) acc[i][j] = (floatx4){0.f, 0.f, 0.f, 0.f};

        auto stage = [&](int buf, int kk) {
            ushort* as = As + buf * 2048;
            ushort* bs = Bs + buf * 2048;
            gload_lds16(A  + (size_t)(row0 + wave * 16 + sr) * K + kk + sc, &as[(wave * 16) * 32]);
            gload_lds16(BT + (size_t)(col0 + wave * 16 + sr) * K + kk + sc, &bs[(wave * 16) * 32]);
        };

        __syncthreads();   // SH free from phase 2
        stage(0, 0);

        for (int ki = 0; ki < 32; ++ki) {
            __syncthreads();
            if (ki + 1 < 32) stage((ki + 1) & 1, (ki + 1) << 5);
            const ushort* as = As + (ki & 1) * 2048;
            const ushort* bs = Bs + (ki & 1) * 2048;

            short8 af[2], bfr[2];
#pragma unroll
            for (int i = 0; i < 2; ++i)
                af[i] = *(const short8*)&as[(wm + i * 16 + l15) * 32 + quad * 8];
#pragma unroll
            for (int j = 0; j < 2; ++j)
                bfr[j] = *(const short8*)&bs[(wn + j * 16 + l15) * 32 + quad * 8];
#pragma unroll
            for (int i = 0; i < 2; ++i)
#pragma unroll
                for (int j = 0; j < 2; ++j)
                    acc[i][j] = __builtin_amdgcn_mfma_f32_16x16x32_bf16(af[i], bfr[j], acc[i][j], 0, 0, 0);
        }

#pragma unroll
        for (int j = 0; j < 2; ++j) {
            int col = col0 + wn + j * 16 + l15;
            float bb = p.bproj[col];
#pragma unroll
            for (int i = 0; i < 2; ++i) {
                int rowb = row0 + wm + i * 16 + quad * 4;
#pragma unroll
                for (int r = 0; r < 4; ++r)
                    p.out[(size_t)(rowb + r) * CDIM + col] = acc[i][j][r] + bb;
            }
        }
    }
}

// ---------------------------------------------------------------------------
extern "C" void kernel_launch(void* const* d_in, const int* in_sizes, int n_in,
                              void* d_out, int out_size, void* d_ws, size_t ws_size,
                              hipStream_t stream)
{
    const float* x          = (const float*)d_in[0];
    const int*   frame_ids  = (const int*)d_in[1];
    const int*   is_hub     = (const int*)d_in[2];
    const int*   adj        = (const int*)d_in[3];
    const float* frame_bias = (const float*)d_in[4];
    const float* Wqkv       = (const float*)d_in[5];
    const float* bqkv       = (const float*)d_in[6];
    const float* Wproj      = (const float*)d_in[7];
    const float* bproj      = (const float*)d_in[8];
    float* out = (float*)d_out;

    // workspace layout (ushort units)
    ushort* xb     = (ushort*)d_ws;            // 2048*1024
    ushort* wqkvT  = xb     + 2097152;         // 3072*1024
    ushort* wprojT = wqkvT  + 3145728;         // 1024*1024
    ushort* qkvb   = wprojT + 1048576;         // [2][H][N][D] used
    ushort* vTb    = qkvb   + 6291456;         // 16*64*2048
    ushort* attnb  = vTb    + 2097152;         // 2048*1024
    u64*    hubmask = (u64*)(attnb + 2097152); // 32 x u64

    KParams p;
    p.x = x; p.frame_ids = frame_ids; p.is_hub = is_hub; p.adj = adj;
    p.frame_bias = frame_bias; p.Wqkv = Wqkv; p.bqkv = bqkv;
    p.Wproj = Wproj; p.bproj = bproj; p.out = out;
    p.xb = xb; p.wqkvT = wqkvT; p.wprojT = wprojT;
    p.qkvb = qkvb; p.vTb = vTb; p.attnb = attnb; p.hubmask = hubmask;

    // host-side, stream-free, capture-safe viability gate for cooperative launch
    bool launched = false;
    int dev = 0;
    (void)hipGetDevice(&dev);
    int coopAttr = 0;
    (void)hipDeviceGetAttribute(&coopAttr, hipDeviceAttributeCooperativeLaunch, dev);
    int maxBlk = 0;
    hipError_t qe = hipOccupancyMaxActiveBlocksPerMultiprocessor(
        &maxBlk, (const void*)fused_kernel, 256, 0);
    if (coopAttr && qe == hipSuccess && maxBlk >= 2) {
        void* kargs[] = { (void*)&p };
        hipError_t le = hipLaunchCooperativeKernel((const void*)fused_kernel,
                                                   dim3(512), dim3(256),
                                                   kargs, 0, stream);
        if (le == hipSuccess) launched = true;
        else (void)hipGetLastError();   // clear sticky error before fallback
    }

    if (!launched) {
        // R11-validated 4-dispatch pipeline (154.3 us)
        prep_kernel<<<dim3(3073), dim3(256), 0, stream>>>(
            x, xb, Wqkv, wqkvT, Wproj, wprojT, is_hub, hubmask);
        gemm_bt_kernel<<<dim3(3 * CDIM / 128, NTOK / 128), dim3(256), 0, stream>>>(
            xb, wqkvT, bqkv, qkvb, vTb, NTOK, 3 * CDIM, CDIM, 1);
        attn_tile_kernel<<<dim3(512), dim3(256), 0, stream>>>(
            qkvb, vTb, frame_ids, hubmask, adj, frame_bias, attnb);
        gemm_bt_kernel<<<dim3(CDIM / 128, NTOK / 128), dim3(256), 0, stream>>>(
            attnb, wprojT, bproj, out, nullptr, NTOK, CDIM, CDIM, 0);
    }
}

// Round 15
// 155.409 us; speedup vs baseline: 1.0111x; 1.0034x over previous
//
#include <hip/hip_runtime.h>

#define NTOK 2048
#define CDIM 1024
#define NHEAD 16
#define HDIM 64
#define NFRM 8
#define FTOK 256

typedef unsigned short ushort;
typedef unsigned long long u64;
typedef __attribute__((ext_vector_type(8))) short short8;     // 8 bf16 = 4 VGPRs (MFMA A/B frag)
typedef __attribute__((ext_vector_type(8))) ushort ushort8;
typedef __attribute__((ext_vector_type(4))) ushort ushort4v;
typedef __attribute__((ext_vector_type(4))) float floatx4;    // MFMA C/D frag

__device__ __forceinline__ ushort f2bf(float f) {
    unsigned int u = __float_as_uint(f);
    return (ushort)((u + 0x7fffu + ((u >> 16) & 1u)) >> 16);   // RNE
}

// async global->LDS, 16B per lane; LDS dest = wave-uniform base + lane*16
__device__ __forceinline__ void gload_lds16(const void* g, void* l) {
    __builtin_amdgcn_global_load_lds(
        (const __attribute__((address_space(1))) unsigned int*)(uintptr_t)g,
        (__attribute__((address_space(3))) unsigned int*)(unsigned int)(uintptr_t)l,
        16, 0, 0);
}

// ---------------------------------------------------------------------------
// Fused prep: [0,2048) x fp32->bf16 ; [2048,2816) Wqkv^T ; [2816,3072) Wproj^T
// [3072] hub bitmask
// ---------------------------------------------------------------------------
__global__ __launch_bounds__(256)
void prep_kernel(const float* __restrict__ x, ushort* __restrict__ xb,
                 const float* __restrict__ Wqkv, ushort* __restrict__ wqkvT,
                 const float* __restrict__ Wproj, ushort* __restrict__ wprojT,
                 const int* __restrict__ is_hub, u64* __restrict__ hubmask)
{
    __shared__ ushort LT[64][72];
    const int b = blockIdx.x, t = threadIdx.x;

    if (b < 2048) {
        int i = b * 256 + t;
        float4 f = ((const float4*)x)[i];
        ushort4v o = { f2bf(f.x), f2bf(f.y), f2bf(f.z), f2bf(f.w) };
        ((ushort4v*)xb)[i] = o;
        return;
    }
    if (b >= 3072) {
        if (t < NTOK / 64) {
            u64 m = 0;
            for (int j = 0; j < 64; ++j)
                m |= (u64)(is_hub[t * 64 + j] != 0) << j;
            hubmask[t] = m;
        }
        return;
    }

    const float* W; ushort* WT; int K, N, n0, k0;
    if (b < 2816) { int idx = b - 2048; W = Wqkv;  WT = wqkvT;  K = 1024; N = 3072;
                    n0 = (idx % 48) * 64; k0 = (idx / 48) * 64; }
    else          { int idx = b - 2816; W = Wproj; WT = wprojT; K = 1024; N = 1024;
                    n0 = (idx & 15) * 64; k0 = (idx >> 4) * 64; }

    const int kr = t >> 4, nc = t & 15;
#pragma unroll
    for (int i = 0; i < 4; ++i) {
        int k = kr + i * 16;
        float4 w4 = *(const float4*)(W + (size_t)(k0 + k) * N + n0 + nc * 4);
        LT[nc*4+0][k] = f2bf(w4.x);
        LT[nc*4+1][k] = f2bf(w4.y);
        LT[nc*4+2][k] = f2bf(w4.z);
        LT[nc*4+3][k] = f2bf(w4.w);
    }
    __syncthreads();
    const int n = t >> 2;
#pragma unroll
    for (int half = 0; half < 2; ++half) {
        int kc = (t & 3) + 4 * half;
        ushort8 v = *(const ushort8*)&LT[n][kc * 8];
        *(ushort8*)(WT + (size_t)(n0 + n) * K + k0 + kc * 8) = v;
    }
}

// ---------------------------------------------------------------------------
// bf16 MFMA GEMM: C = A[M,K] @ BT[N,K]^T + bias
// 128x128 tile, 4 waves (2x2), BK=32, dbuf global_load_lds staging (R11).
// R15: LDS-strip epilogues — C fragments round-trip through a wave-private
// 16x72 strip, then coalesced wide stores. Replaces the R11 scalar scatters
// (Q/K: 64x global_store_short/thread; V^T: 64 instr x 64 cache lines).
// mode 0: fp32 [M][N] via float strip + float4 rows (256B segments)
// mode 1: Q,K -> qkvb [2][H][N][D] (ushort8 rows); V -> vTb [H][D][N]
// ---------------------------------------------------------------------------
__global__ __launch_bounds__(256)
void gemm_bt_kernel(const ushort* __restrict__ A, const ushort* __restrict__ BT,
                    const float* __restrict__ bias, void* __restrict__ out,
                    ushort* __restrict__ vtb,
                    int M, int N, int K, int mode)
{
    __shared__ ushort As[2][128 * 32];
    __shared__ ushort Bs[2][128 * 32];

    const int t = threadIdx.x;
    const int wave = t >> 6, lane = t & 63;
    const int quad = lane >> 4, l15 = lane & 15;
    const int row0 = blockIdx.y * 128, col0 = blockIdx.x * 128;
    const int wm = (wave >> 1) * 64, wn = (wave & 1) * 64;

    const int sr = lane >> 2, sc = (lane & 3) * 8;
    const int r0 = wave * 32;

    floatx4 acc[4][4];
#pragma unroll
    for (int i = 0; i < 4; ++i)
#pragma unroll
        for (int j = 0; j < 4; ++j) acc[i][j] = (floatx4){0.f, 0.f, 0.f, 0.f};

    gload_lds16(A  + (size_t)(row0 + r0      + sr) * K + sc, &As[0][ r0       * 32]);
    gload_lds16(A  + (size_t)(row0 + r0 + 16 + sr) * K + sc, &As[0][(r0 + 16) * 32]);
    gload_lds16(BT + (size_t)(col0 + r0      + sr) * K + sc, &Bs[0][ r0       * 32]);
    gload_lds16(BT + (size_t)(col0 + r0 + 16 + sr) * K + sc, &Bs[0][(r0 + 16) * 32]);

    const int nk = K >> 5;
    for (int ki = 0; ki < nk; ++ki) {
        __syncthreads();
        if (ki + 1 < nk) {
            const int kn = (ki + 1) << 5;
            const int b = (ki + 1) & 1;
            gload_lds16(A  + (size_t)(row0 + r0      + sr) * K + kn + sc, &As[b][ r0       * 32]);
            gload_lds16(A  + (size_t)(row0 + r0 + 16 + sr) * K + kn + sc, &As[b][(r0 + 16) * 32]);
            gload_lds16(BT + (size_t)(col0 + r0      + sr) * K + kn + sc, &Bs[b][ r0       * 32]);
            gload_lds16(BT + (size_t)(col0 + r0 + 16 + sr) * K + kn + sc, &Bs[b][(r0 + 16) * 32]);
        }
        const ushort* as = As[ki & 1];
        const ushort* bs = Bs[ki & 1];

        short8 af[4], bfr[4];
#pragma unroll
        for (int i = 0; i < 4; ++i)
            af[i] = *(const short8*)&as[(wm + i * 16 + l15) * 32 + quad * 8];
#pragma unroll
        for (int j = 0; j < 4; ++j)
            bfr[j] = *(const short8*)&bs[(wn + j * 16 + l15) * 32 + quad * 8];
#pragma unroll
        for (int i = 0; i < 4; ++i)
#pragma unroll
            for (int j = 0; j < 4; ++j)
                acc[i][j] = __builtin_amdgcn_mfma_f32_16x16x32_bf16(af[i], bfr[j], acc[i][j], 0, 0, 0);
    }

    __syncthreads();   // staging LDS free -> reuse as epilogue strips

    if (mode == 0) {
        // wave-private float strip 16x68 inside As/Bs space (4 x 4352 B)
        float* stripf = (float*)&As[0][0] + wave * (16 * 68);
        float bb[4];
#pragma unroll
        for (int j = 0; j < 4; ++j) bb[j] = bias[col0 + wn + j * 16 + l15];
        float* outf = (float*)out;

#pragma unroll
        for (int i = 0; i < 4; ++i) {
#pragma unroll
            for (int j = 0; j < 4; ++j)
#pragma unroll
                for (int r = 0; r < 4; ++r)
                    stripf[(quad * 4 + r) * 68 + j * 16 + l15] = acc[i][j][r] + bb[j];
            // wave-synchronous: compiler inserts lgkmcnt wait before reads
#pragma unroll
            for (int c = 0; c < 4; ++c) {
                int idx = c * 64 + lane;
                int row = idx >> 4, ch = idx & 15;
                float4 v4 = *(const float4*)&stripf[row * 68 + ch * 4];
                *(float4*)(outf + (size_t)(row0 + wm + i * 16 + row) * N
                                  + col0 + wn + ch * 4) = v4;
            }
        }
    } else {
        // wave-private ushort strip 16x72 (4 x 2304 B)
        ushort* strip = &As[0][0] + wave * (16 * 72);
        float bb[4];
#pragma unroll
        for (int j = 0; j < 4; ++j) bb[j] = bias[col0 + wn + j * 16 + l15];

        // wave's 64 cols = one (part, head), full d range (col0+wn % 64 == 0)
        const int cw = col0 + wn;
        const int part = cw >> 10, hh = (cw >> 6) & 15;

#pragma unroll
        for (int i = 0; i < 4; ++i) {
            const int tok0 = row0 + wm + i * 16;
#pragma unroll
            for (int j = 0; j < 4; ++j)
#pragma unroll
                for (int r = 0; r < 4; ++r)
                    strip[(quad * 4 + r) * 72 + j * 16 + l15] = f2bf(acc[i][j][r] + bb[j]);

            if (part < 2) {
                // Q,K: [part][H][N][D] — rows contiguous along d (128 B)
                ushort* gdst = (ushort*)out + ((size_t)(part * NHEAD + hh) * NTOK) * HDIM;
#pragma unroll
                for (int c = 0; c < 2; ++c) {
                    int idx = c * 64 + lane;
                    int row = idx >> 3, ch = idx & 7;
                    ushort8 v8 = *(const ushort8*)&strip[row * 72 + ch * 8];
                    *(ushort8*)(gdst + (size_t)(tok0 + row) * HDIM + ch * 8) = v8;
                }
            } else {
                // V -> vT [H][D][N]: per d-row, 16 tokens = 2 ushort8 along n
                ushort* vdst = vtb + (size_t)hh * HDIM * NTOK;
#pragma unroll
                for (int c = 0; c < 2; ++c) {
                    int idx = c * 64 + lane;
                    int d = idx >> 1, tch = idx & 1;
                    ushort8 v8;
#pragma unroll
                    for (int k = 0; k < 8; ++k)
                        v8[k] = strip[(tch * 8 + k) * 72 + d];
                    *(ushort8*)(vdst + (size_t)d * NTOK + tok0 + tch * 8) = v8;
                }
            }
        }
    }
}

// ---------------------------------------------------------------------------
// Staged MFMA flash attention (R11-validated, unchanged): block = (head,
// 64-q tile), 4 waves. Coalesced 1KB/instr staging, +72 padded rows (2-way
// max bank conflicts), dbuf staging (prefetch flies one compute phase),
// no-max softmax, XCD-locked heads, hubmask bit-tests.
// ---------------------------------------------------------------------------
__global__ __launch_bounds__(256)
void attn_tile_kernel(const ushort* __restrict__ qkvb,   // [2][H][N][D] bf16 (Q,K)
                      const ushort* __restrict__ vTb,    // [H][D][N] bf16
                      const int* __restrict__ frame_ids,
                      const u64* __restrict__ hubmask,   // [NTOK/64]
                      const int* __restrict__ adj,
                      const float* __restrict__ frame_bias,
                      ushort* __restrict__ attnb)        // [N][C] bf16
{
    __shared__ ushort Ks [2][64 * 72];
    __shared__ ushort VTs[2][64 * 72];
    __shared__ ushort Ps [4][16 * 72];

    const int t = threadIdx.x;
    const int wave = t >> 6, lane = t & 63;
    const int quad = lane >> 4, l15 = lane & 15;
    const int b = blockIdx.x;
    const int h = b & 15, q0 = (b >> 4) * 64;   // XCD-locking swizzle

    const ushort* Qg = qkvb + ((size_t)h * NTOK) * HDIM;
    const ushort* Kg = qkvb + ((size_t)(NHEAD + h) * NTOK) * HDIM;
    const ushort* Vg = vTb + ((size_t)h * HDIM) * NTOK;

    short8 aq0 = *(const short8*)(Qg + (size_t)(q0 + wave * 16 + l15) * HDIM + quad * 8);
    short8 aq1 = *(const short8*)(Qg + (size_t)(q0 + wave * 16 + l15) * HDIM + 32 + quad * 8);

    const int fq = frame_ids[q0];
    unsigned vpack = 0; int nv = 0;
#pragma unroll
    for (int f = 0; f < NFRM; ++f)
        if (adj[fq * NFRM + f]) { vpack |= (unsigned)f << (3 * nv); ++nv; }
    const int ntot = nv * 4;

    const u64 hmq = hubmask[q0 >> 6];
    int qh[4];
#pragma unroll
    for (int r = 0; r < 4; ++r) qh[r] = (int)((hmq >> (wave * 16 + quad * 4 + r)) & 1);

    float lpart[4] = {0.f, 0.f, 0.f, 0.f};
    floatx4 oacc[4];
#pragma unroll
    for (int dt = 0; dt < 4; ++dt) oacc[dt] = (floatx4){0.f, 0.f, 0.f, 0.f};

    const int sro = wave * 16 + (lane >> 3);
    const int sc  = (lane & 7) * 8;

    auto tile_k0 = [&](int vt) -> int {
        const int fj = (int)((vpack >> (3 * (vt >> 2))) & 7u);
        return fj * FTOK + (vt & 3) * 64;
    };

    auto stage = [&](int vt) {
        const int k0 = tile_k0(vt);
        const int bf = vt & 1;
        ushort8 k8a = *(const ushort8*)(Kg + (size_t)(k0 + sro)     * HDIM + sc);
        ushort8 k8b = *(const ushort8*)(Kg + (size_t)(k0 + sro + 8) * HDIM + sc);
        ushort8 v8a = *(const ushort8*)(Vg + (size_t)(sro)     * NTOK + k0 + sc);
        ushort8 v8b = *(const ushort8*)(Vg + (size_t)(sro + 8) * NTOK + k0 + sc);
        *(ushort8*)&Ks [bf][ sro      * 72 + sc] = k8a;
        *(ushort8*)&Ks [bf][(sro + 8) * 72 + sc] = k8b;
        *(ushort8*)&VTs[bf][ sro      * 72 + sc] = v8a;
        *(ushort8*)&VTs[bf][(sro + 8) * 72 + sc] = v8b;
    };

    stage(0);

    for (int vt = 0; vt < ntot; ++vt) {
        __syncthreads();
        if (vt + 1 < ntot) stage(vt + 1);

        const int fj = (int)((vpack >> (3 * (vt >> 2))) & 7u);
        const int k0 = fj * FTOK + (vt & 3) * 64;
        const float fb = frame_bias[fq * NFRM + fj];
        const bool same = (fj == fq);
        const u64 hmk = hubmask[k0 >> 6];
        const ushort* ks = Ks[vt & 1];
        const ushort* vs = VTs[vt & 1];

        floatx4 s[4];
#pragma unroll
        for (int nt = 0; nt < 4; ++nt) {
            short8 bk0 = *(const short8*)&ks[(nt * 16 + l15) * 72 + quad * 8];
            short8 bk1 = *(const short8*)&ks[(nt * 16 + l15) * 72 + 32 + quad * 8];
            s[nt] = (floatx4){0.f, 0.f, 0.f, 0.f};
            s[nt] = __builtin_amdgcn_mfma_f32_16x16x32_bf16(aq0, bk0, s[nt], 0, 0, 0);
            s[nt] = __builtin_amdgcn_mfma_f32_16x16x32_bf16(aq1, bk1, s[nt], 0, 0, 0);
        }

#pragma unroll
        for (int r = 0; r < 4; ++r) {
            float ps = 0.f;
#pragma unroll
            for (int nt = 0; nt < 4; ++nt) {
                int kh = (int)((hmk >> (nt * 16 + l15)) & 1);
                bool allow = same || ((qh[r] == 0) && (kh == 0));
                float sv = allow ? fmaf(s[nt][r], 0.125f, fb) : -1.0e30f;
                float p = __expf(sv);
                ps += p;
                Ps[wave][(quad * 4 + r) * 72 + nt * 16 + l15] = f2bf(p);
            }
            lpart[r] += ps;
        }

        short8 ap0 = *(const short8*)&Ps[wave][l15 * 72 + quad * 8];
        short8 ap1 = *(const short8*)&Ps[wave][l15 * 72 + 32 + quad * 8];
#pragma unroll
        for (int dt = 0; dt < 4; ++dt) {
            short8 bv0 = *(const short8*)&vs[(dt * 16 + l15) * 72 + quad * 8];
            short8 bv1 = *(const short8*)&vs[(dt * 16 + l15) * 72 + 32 + quad * 8];
            oacc[dt] = __builtin_amdgcn_mfma_f32_16x16x32_bf16(ap0, bv0, oacc[dt], 0, 0, 0);
            oacc[dt] = __builtin_amdgcn_mfma_f32_16x16x32_bf16(ap1, bv1, oacc[dt], 0, 0, 0);
        }
    }

    float linv[4];
#pragma unroll
    for (int r = 0; r < 4; ++r) {
        float ls = lpart[r];
        ls += __shfl_xor(ls, 1);
        ls += __shfl_xor(ls, 2);
        ls += __shfl_xor(ls, 4);
        ls += __shfl_xor(ls, 8);
        linv[r] = 1.0f / ls;
    }

#pragma unroll
    for (int dt = 0; dt < 4; ++dt) {
        int col = h * HDIM + dt * 16 + l15;
#pragma unroll
        for (int r = 0; r < 4; ++r) {
            int row = q0 + wave * 16 + quad * 4 + r;
            attnb[(size_t)row * CDIM + col] = f2bf(oacc[dt][r] * linv[r]);
        }
    }
}

// ---------------------------------------------------------------------------
extern "C" void kernel_launch(void* const* d_in, const int* in_sizes, int n_in,
                              void* d_out, int out_size, void* d_ws, size_t ws_size,
                              hipStream_t stream)
{
    const float* x          = (const float*)d_in[0];
    const int*   frame_ids  = (const int*)d_in[1];
    const int*   is_hub     = (const int*)d_in[2];
    const int*   adj        = (const int*)d_in[3];
    const float* frame_bias = (const float*)d_in[4];
    const float* Wqkv       = (const float*)d_in[5];
    const float* bqkv       = (const float*)d_in[6];
    const float* Wproj      = (const float*)d_in[7];
    const float* bproj      = (const float*)d_in[8];
    float* out = (float*)d_out;

    // workspace layout (ushort units)
    ushort* xb     = (ushort*)d_ws;            // 2048*1024
    ushort* wqkvT  = xb     + 2097152;         // 3072*1024
    ushort* wprojT = wqkvT  + 3145728;         // 1024*1024
    ushort* qkvb   = wprojT + 1048576;         // [2][H][N][D] used
    ushort* vTb    = qkvb   + 6291456;         // 16*64*2048
    ushort* attnb  = vTb    + 2097152;         // 2048*1024
    u64*    hubmask = (u64*)(attnb + 2097152); // 32 x u64

    prep_kernel<<<dim3(3073), dim3(256), 0, stream>>>(
        x, xb, Wqkv, wqkvT, Wproj, wprojT, is_hub, hubmask);

    gemm_bt_kernel<<<dim3(3 * CDIM / 128, NTOK / 128), dim3(256), 0, stream>>>(
        xb, wqkvT, bqkv, qkvb, vTb, NTOK, 3 * CDIM, CDIM, 1);

    attn_tile_kernel<<<dim3(512), dim3(256), 0, stream>>>(
        qkvb, vTb, frame_ids, hubmask, adj, frame_bias, attnb);

    gemm_bt_kernel<<<dim3(CDIM / 128, NTOK / 128), dim3(256), 0, stream>>>(
        attnb, wprojT, bproj, out, nullptr, NTOK, CDIM, CDIM, 0);
}